// Round 14
// baseline (174.769 us; speedup 1.0000x reference)
//
#include <hip/hip_runtime.h>
#include <math.h>

// RiskGAT: 2-layer GAT (PyG GATConv, concat=True, self-loops) + linear + sigmoid.
// N=100000, E=1600000. L1: in=4,H=4,D=16 (F=64). L2: in=64,H=2,D=8 (F=16).
//
// R12 -> R14 (R13 hit GPUAcquisitionTimeout; resubmit with a fix for a latent bug
// found on re-review: R13's sW2 load only covered [0,768) at 1024 threads).
// R12 counters showed kbA1 occupancy is GRID-limited (391 blocks x 512thr
// = 12 waves/CU = 30%), latency-bound (VALUBusy 21%, HBM 6%). Fix: 1024-THREAD BLOCKS
// for kbA1/kbA2 (16 waves/block -> ~24 waves/CU): agg in ONE pass (256 nodes x 4 lanes);
// kbA1 epilogue runs in 2 phases of 128 nodes sharing the 33KB sE buffer (sE rows are
// same-wave-private, so one barrier between phases). Sort/csr-handoff/lane-split kept.

#define NEG_SLOPE 0.2f
#define SHIFT 8                 // 256 nodes per bucket
#define BN 256
#define BMASK 255
#define CAPB 8192               // per-bucket region capacity (mean ~4092, >60-sigma)
#define STCAP 6144              // LDS stage capacity (mean ~4092, >30-sigma)

__device__ __forceinline__ float lrelu(float v) { return v >= 0.f ? v : NEG_SLOPE * v; }
__device__ __forceinline__ float sel4(int tt, float v0, float v1, float v2, float v3) {
    return tt == 0 ? v0 : tt == 1 ? v1 : tt == 2 ? v2 : v3;
}
#define RED4(v) { v += __shfl_xor(v, 1); v += __shfl_xor(v, 2); }

// ---------------- Pass A: scatter packed (dlocal<<17 | src) into bucket regions ----------
__global__ void kb_scatter(const int* __restrict__ src, const int* __restrict__ dst,
                           int* __restrict__ bcur, unsigned* __restrict__ ebuf, int E) {
    __shared__ int lh[512], lbase[512], loff[512];
    int t = threadIdx.x;
    lh[t] = 0; lh[t + 256] = 0;
    __syncthreads();
    const int4* src4 = reinterpret_cast<const int4*>(src);
    const int4* dst4 = reinterpret_cast<const int4*>(dst);
    int base4 = blockIdx.x * 1024;           // 4096 edges = 1024 int4
    int myb[16];
    unsigned myv[16];
#pragma unroll
    for (int it = 0; it < 4; ++it) {
        int i4 = base4 + it * 256 + t;
        if (i4 * 4 < E) {                    // E % 4 == 0
            int4 s4 = src4[i4], d4 = dst4[i4];
            int ss[4] = {s4.x, s4.y, s4.z, s4.w};
            int dd[4] = {d4.x, d4.y, d4.z, d4.w};
#pragma unroll
            for (int c = 0; c < 4; ++c) {
                int b = dd[c] >> SHIFT;
                myb[it * 4 + c] = b;
                myv[it * 4 + c] = (unsigned)ss[c] | ((unsigned)(dd[c] & BMASK) << 17);
                atomicAdd(&lh[b], 1);
            }
        } else {
#pragma unroll
            for (int c = 0; c < 4; ++c) myb[it * 4 + c] = -1;
        }
    }
    __syncthreads();
    if (lh[t]) lbase[t] = atomicAdd(&bcur[t], lh[t]);
    if (lh[t + 256]) lbase[t + 256] = atomicAdd(&bcur[t + 256], lh[t + 256]);
    loff[t] = 0; loff[t + 256] = 0;
    __syncthreads();
#pragma unroll
    for (int it = 0; it < 16; ++it) {
        int b = myb[it];
        if (b >= 0) {
            int o = lbase[b] + atomicAdd(&loff[b], 1);
            if (o < CAPB) ebuf[(size_t)b * CAPB + o] = myv[it];
        }
    }
}

// ---------------- kbA1: LDS sort -> csr writeback -> lane-split L1 agg + epilogue ---------
__global__ void __launch_bounds__(1024) kbA1(
        const float* __restrict__ x, const float* __restrict__ W1,
        const float* __restrict__ as1, const float* __restrict__ ad1,
        const float* __restrict__ b1, const float* __restrict__ W2,
        const float* __restrict__ as2, const float* __restrict__ ad2,
        const int* __restrict__ bcur, const unsigned* __restrict__ ebuf,
        int* __restrict__ csr, int* __restrict__ cnt, int* __restrict__ rstart,
        float* __restrict__ h2, float* __restrict__ als2, float* __restrict__ ald2, int N)
{
    __shared__ float sW[256], swals[16], swald[16], sb1[64], sW2[1024], sas2[16], sad2[16];
    __shared__ float aldL[BN * 5];       // [dl][head] stride 5
    __shared__ int nh[BN], ns[BN], stmp[BN];
    __shared__ int stage[STCAP];
    __shared__ float sE[128 * 65];       // 128 nodes/phase x 64 e0, stride 65
    int t = threadIdx.x, b = blockIdx.x;
    if (t < 256) { sW[t] = W1[t]; nh[t] = 0; }
    sW2[t] = W2[t];                      // blockDim == 1024 == |W2|
    if (t < 64) sb1[t] = b1[t];
    if (t >= 64 && t < 80) { sas2[t - 64] = as2[t - 64]; sad2[t - 64] = ad2[t - 64]; }
    __syncthreads();
    if (t < 16) {
        int head = t >> 2, i = t & 3;
        float s1 = 0.f, s2 = 0.f;
        for (int d = 0; d < 16; ++d) {
            float w = sW[i * 64 + head * 16 + d];
            s1 += w * as1[head * 16 + d];
            s2 += w * ad1[head * 16 + d];
        }
        swals[t] = s1;    // (W1_h @ a_src_h)[i]
        swald[t] = s2;
    }
    __syncthreads();

    int node0 = b << SHIFT;
    int nn = min(BN, N - node0);
    const float4* x4 = reinterpret_cast<const float4*>(x);
    int ne = min(bcur[b], STCAP);
    const unsigned* eb = ebuf + (size_t)b * CAPB;

    // hist + per-dst ald precompute
    for (int i = t; i < ne; i += 1024) atomicAdd(&nh[eb[i] >> 17], 1);
    for (int j = t; j < nn; j += 1024) {
        float4 xd = x4[node0 + j];
#pragma unroll
        for (int h = 0; h < 4; ++h)
            aldL[j * 5 + h] = xd.x * swald[h * 4 + 0] + xd.y * swald[h * 4 + 1]
                            + xd.z * swald[h * 4 + 2] + xd.w * swald[h * 4 + 3];
    }
    __syncthreads();

    // scan (exclusive) -> ns cursor
    int vcnt = 0;
    if (t < 256) { vcnt = nh[t]; stmp[t] = vcnt; }
    __syncthreads();
#pragma unroll
    for (int off = 1; off < 256; off <<= 1) {
        int a = 0;
        if (t < 256 && t >= off) a = stmp[t - off];
        __syncthreads();
        if (t < 256) stmp[t] += a;
        __syncthreads();
    }
    if (t < 256) ns[t] = stmp[t] - vcnt;
    __syncthreads();

    // counting-sort into LDS stage (src only; dl implied by segment)
    for (int i = t; i < ne; i += 1024) {
        unsigned pk = eb[i];
        int pos = atomicAdd(&ns[pk >> 17], 1);
        stage[pos] = (int)(pk & 0x1FFFFu);
    }
    __syncthreads();

    // ---- write sorted list + cnt/rstart to global for kbA2 (coalesced) ----
    {
        int lim4 = ne & ~3;
        const int4* st4 = reinterpret_cast<const int4*>(stage);
        int4* c4 = reinterpret_cast<int4*>(csr + (size_t)b * CAPB);
        for (int i = t; i * 4 < lim4; i += 1024) c4[i] = st4[i];
        for (int i = lim4 + t; i < ne; i += 1024) csr[(size_t)b * CAPB + i] = stage[i];
        for (int j = t; j < nn; j += 1024) {
            cnt[node0 + j] = nh[j];
            rstart[node0 + j] = b * CAPB + ns[j] - nh[j];
        }
    }

    // ---- agg: ONE pass, 256 nodes x 4 lanes; edges split across the node's lanes ----
    int g = t >> 2, tt = t & 3;          // g in [0,256)
    float wa00 = swals[0],  wa01 = swals[1],  wa02 = swals[2],  wa03 = swals[3];
    float wa10 = swals[4],  wa11 = swals[5],  wa12 = swals[6],  wa13 = swals[7];
    float wa20 = swals[8],  wa21 = swals[9],  wa22 = swals[10], wa23 = swals[11];
    float wa30 = swals[12], wa31 = swals[13], wa32 = swals[14], wa33 = swals[15];
    int j = g;
    int n = node0 + j;
    bool act = j < nn;
    int e = act ? nh[j] : 0;
    int st = act ? (ns[j] - e) : 0;      // cursor ended at start+cnt
    float al0 = act ? aldL[j * 5 + 0] : 0.f;
    float al1 = act ? aldL[j * 5 + 1] : 0.f;
    float al2 = act ? aldL[j * 5 + 2] : 0.f;
    float al3 = act ? aldL[j * 5 + 3] : 0.f;
    float dn0 = 0.f, dn1 = 0.f, dn2 = 0.f, dn3 = 0.f;
    float a00 = 0.f, a01 = 0.f, a02 = 0.f, a03 = 0.f;
    float a10 = 0.f, a11 = 0.f, a12 = 0.f, a13 = 0.f;
    float a20 = 0.f, a21 = 0.f, a22 = 0.f, a23 = 0.f;
    float a30 = 0.f, a31 = 0.f, a32 = 0.f, a33 = 0.f;
    for (int i = tt; i < e; i += 4) {
        int s = stage[st + i];
        float4 xs = x4[s];
        float v0 = lrelu(fmaf(xs.x, wa00, fmaf(xs.y, wa01, fmaf(xs.z, wa02, fmaf(xs.w, wa03, al0)))));
        float v1 = lrelu(fmaf(xs.x, wa10, fmaf(xs.y, wa11, fmaf(xs.z, wa12, fmaf(xs.w, wa13, al1)))));
        float v2 = lrelu(fmaf(xs.x, wa20, fmaf(xs.y, wa21, fmaf(xs.z, wa22, fmaf(xs.w, wa23, al2)))));
        float v3 = lrelu(fmaf(xs.x, wa30, fmaf(xs.y, wa31, fmaf(xs.z, wa32, fmaf(xs.w, wa33, al3)))));
        float p0 = __expf(v0), p1 = __expf(v1), p2 = __expf(v2), p3 = __expf(v3);
        dn0 += p0; dn1 += p1; dn2 += p2; dn3 += p3;
        a00 = fmaf(p0, xs.x, a00); a01 = fmaf(p0, xs.y, a01);
        a02 = fmaf(p0, xs.z, a02); a03 = fmaf(p0, xs.w, a03);
        a10 = fmaf(p1, xs.x, a10); a11 = fmaf(p1, xs.y, a11);
        a12 = fmaf(p1, xs.z, a12); a13 = fmaf(p1, xs.w, a13);
        a20 = fmaf(p2, xs.x, a20); a21 = fmaf(p2, xs.y, a21);
        a22 = fmaf(p2, xs.z, a22); a23 = fmaf(p2, xs.w, a23);
        a30 = fmaf(p3, xs.x, a30); a31 = fmaf(p3, xs.y, a31);
        a32 = fmaf(p3, xs.z, a32); a33 = fmaf(p3, xs.w, a33);
    }
    // allreduce across the 4 lanes of this node
    RED4(dn0) RED4(dn1) RED4(dn2) RED4(dn3)
    RED4(a00) RED4(a01) RED4(a02) RED4(a03)
    RED4(a10) RED4(a11) RED4(a12) RED4(a13)
    RED4(a20) RED4(a21) RED4(a22) RED4(a23)
    RED4(a30) RED4(a31) RED4(a32) RED4(a33)
    // lane tt takes head tt
    float den = sel4(tt, dn0, dn1, dn2, dn3);
    float s0  = sel4(tt, a00, a10, a20, a30);
    float s1  = sel4(tt, a01, a11, a21, a31);
    float s2  = sel4(tt, a02, a12, a22, a32);
    float s3  = sel4(tt, a03, a13, a23, a33);
    // self loop + normalize
    float4 xn = act ? x4[n] : make_float4(0.f, 0.f, 0.f, 0.f);
    float wb0 = swals[tt * 4 + 0], wb1 = swals[tt * 4 + 1];
    float wb2 = swals[tt * 4 + 2], wb3 = swals[tt * 4 + 3];
    float aldv = act ? aldL[j * 5 + tt] : 0.f;
    float als_s = xn.x * wb0 + xn.y * wb1 + xn.z * wb2 + xn.w * wb3;
    float ps = __expf(lrelu(als_s + aldv));
    float inv = 1.f / (den + ps + 1e-16f);
    float a0 = (s0 + ps * xn.x) * inv;
    float a1 = (s1 + ps * xn.y) * inv;
    float a2 = (s2 + ps * xn.z) * inv;
    float a3 = (s3 + ps * xn.w) * inv;

    // ---- epilogue: 2 phases of 128 nodes sharing sE (rows are same-wave-private) ----
    float o0 = 0.f, o1 = 0.f, o2 = 0.f, o3 = 0.f;
#pragma unroll
    for (int ph = 0; ph < 2; ++ph) {
        if ((g >> 7) == ph) {
            int row = g & 127;
#pragma unroll
            for (int d = 0; d < 16; ++d) {
                int col = tt * 16 + d;
                float v = a0 * sW[col] + a1 * sW[64 + col] + a2 * sW[128 + col]
                        + a3 * sW[192 + col] + sb1[col];
                sE[row * 65 + col] = v > 0.f ? v : expm1f(v);
            }
            // same-wave row write->read: ordered by lgkmcnt, no barrier needed
#pragma unroll
            for (int k = 0; k < 64; ++k) {
                float ev = sE[row * 65 + k];
                o0 = fmaf(ev, sW2[k * 16 + tt * 4 + 0], o0);
                o1 = fmaf(ev, sW2[k * 16 + tt * 4 + 1], o1);
                o2 = fmaf(ev, sW2[k * 16 + tt * 4 + 2], o2);
                o3 = fmaf(ev, sW2[k * 16 + tt * 4 + 3], o3);
            }
        }
        __syncthreads();
    }
    if (act)
        reinterpret_cast<float4*>(h2)[(size_t)n * 4 + tt] = make_float4(o0, o1, o2, o3);
    int head2 = tt >> 1, half = tt & 1;
    const float* s2p = sas2 + head2 * 8 + half * 4;
    const float* d2p = sad2 + head2 * 8 + half * 4;
    float qs = o0 * s2p[0] + o1 * s2p[1] + o2 * s2p[2] + o3 * s2p[3];
    float qd = o0 * d2p[0] + o1 * d2p[1] + o2 * d2p[2] + o3 * d2p[3];
    qs += __shfl_xor(qs, 1);
    qd += __shfl_xor(qd, 1);
    if (act && half == 0) {
        als2[n * 2 + head2] = qs;
        ald2[n * 2 + head2] = qd;
    }
}

// ---------------- kbA2: lane-split L2 agg (csr from kbA1) + linear head + sigmoid ---------
__global__ void __launch_bounds__(1024) kbA2(
        const float* __restrict__ h2, const float* __restrict__ als2,
        const float* __restrict__ ald2, const float* __restrict__ b2,
        const float* __restrict__ lw, const float* __restrict__ lb,
        const int* __restrict__ csr, const int* __restrict__ cnt,
        const int* __restrict__ rstart, float* __restrict__ out, int N)
{
    __shared__ float ald2L[BN * 2];
    __shared__ float sb2[16], slw[16];
    int t = threadIdx.x, b = blockIdx.x;
    if (t < 16) { sb2[t] = b2[t]; slw[t] = lw[t]; }
    int node0 = b << SHIFT;
    int nn = min(BN, N - node0);
    for (int j = t; j < nn * 2; j += 1024) ald2L[j] = ald2[node0 * 2 + j];
    __syncthreads();

    const float4* h4 = reinterpret_cast<const float4*>(h2);
    const float2* als22 = reinterpret_cast<const float2*>(als2);
    int g = t >> 2, tt = t & 3;          // g in [0,256)
    int j = g;
    int n = node0 + j;
    bool act = j < nn;
    int e = act ? cnt[n] : 0;
    int st = act ? rstart[n] : 0;
    float al0 = act ? ald2L[j * 2 + 0] : 0.f;
    float al1 = act ? ald2L[j * 2 + 1] : 0.f;
    float d0 = 0.f, d1 = 0.f;
    float c0 = 0.f, c1 = 0.f, c2 = 0.f, c3 = 0.f;
    float c4v = 0.f, c5 = 0.f, c6 = 0.f, c7 = 0.f;
    float c8 = 0.f, c9 = 0.f, c10 = 0.f, c11 = 0.f;
    float c12 = 0.f, c13 = 0.f, c14 = 0.f, c15 = 0.f;
    for (int i = tt; i < e; i += 4) {
        int s = csr[st + i];
        float2 av = als22[s];
        float p0 = __expf(lrelu(av.x + al0));
        float p1 = __expf(lrelu(av.y + al1));
        float4 hA = h4[(size_t)s * 4 + 0], hB = h4[(size_t)s * 4 + 1];
        float4 hC = h4[(size_t)s * 4 + 2], hD = h4[(size_t)s * 4 + 3];
        d0 += p0; d1 += p1;
        c0  = fmaf(p0, hA.x, c0);  c1  = fmaf(p0, hA.y, c1);
        c2  = fmaf(p0, hA.z, c2);  c3  = fmaf(p0, hA.w, c3);
        c4v = fmaf(p0, hB.x, c4v); c5  = fmaf(p0, hB.y, c5);
        c6  = fmaf(p0, hB.z, c6);  c7  = fmaf(p0, hB.w, c7);
        c8  = fmaf(p1, hC.x, c8);  c9  = fmaf(p1, hC.y, c9);
        c10 = fmaf(p1, hC.z, c10); c11 = fmaf(p1, hC.w, c11);
        c12 = fmaf(p1, hD.x, c12); c13 = fmaf(p1, hD.y, c13);
        c14 = fmaf(p1, hD.z, c14); c15 = fmaf(p1, hD.w, c15);
    }
    RED4(d0) RED4(d1)
    RED4(c0) RED4(c1) RED4(c2) RED4(c3)
    RED4(c4v) RED4(c5) RED4(c6) RED4(c7)
    RED4(c8) RED4(c9) RED4(c10) RED4(c11)
    RED4(c12) RED4(c13) RED4(c14) RED4(c15)
    // lane tt owns h2 quad tt (head = tt>>1)
    float t0 = sel4(tt, c0, c4v, c8,  c12);
    float t1 = sel4(tt, c1, c5,  c9,  c13);
    float t2 = sel4(tt, c2, c6,  c10, c14);
    float t3 = sel4(tt, c3, c7,  c11, c15);
    float den = (tt < 2) ? d0 : d1;
    float dot = 0.f;
    if (act) {
        float2 av = als22[n];
        float aldv = (tt < 2) ? al0 : al1;
        float avh = (tt < 2) ? av.x : av.y;
        float ps = __expf(lrelu(avh + aldv));
        float4 hn = h4[(size_t)n * 4 + tt];
        float inv = 1.f / (den + ps + 1e-16f);
        float v0 = (t0 + ps * hn.x) * inv + sb2[tt * 4 + 0];
        float v1 = (t1 + ps * hn.y) * inv + sb2[tt * 4 + 1];
        float v2 = (t2 + ps * hn.z) * inv + sb2[tt * 4 + 2];
        float v3 = (t3 + ps * hn.w) * inv + sb2[tt * 4 + 3];
        v0 = v0 > 0.f ? v0 : expm1f(v0);
        v1 = v1 > 0.f ? v1 : expm1f(v1);
        v2 = v2 > 0.f ? v2 : expm1f(v2);
        v3 = v3 > 0.f ? v3 : expm1f(v3);
        dot = v0 * slw[tt * 4 + 0] + v1 * slw[tt * 4 + 1]
            + v2 * slw[tt * 4 + 2] + v3 * slw[tt * 4 + 3];
    }
    dot += __shfl_xor(dot, 1);
    dot += __shfl_xor(dot, 2);
    if (act && tt == 0) out[n] = 1.f / (1.f + __expf(-(dot + lb[0])));
}

extern "C" void kernel_launch(void* const* d_in, const int* in_sizes, int n_in,
                              void* d_out, int out_size, void* d_ws, size_t ws_size,
                              hipStream_t stream) {
    const float* x     = (const float*)d_in[0];
    const int*   eidx  = (const int*)d_in[1];
    const float* W1    = (const float*)d_in[2];
    const float* as1   = (const float*)d_in[3];
    const float* ad1   = (const float*)d_in[4];
    const float* b1    = (const float*)d_in[5];
    const float* W2    = (const float*)d_in[6];
    const float* as2   = (const float*)d_in[7];
    const float* ad2   = (const float*)d_in[8];
    const float* b2    = (const float*)d_in[9];
    const float* lin_w = (const float*)d_in[10];
    const float* lin_b = (const float*)d_in[11];
    float* out = (float*)d_out;

    const int N = in_sizes[0] / 4;
    const int E = in_sizes[1] / 2;
    const int* src = eidx;
    const int* dst = eidx + E;
    const int NB = (N + BMASK) >> SHIFT;   // 391 buckets of 256 nodes

    // ---- workspace layout ----
    int*      bcur   = (int*)d_ws;                         // 512
    unsigned* ebuf   = (unsigned*)(bcur + 512);            // NB*CAPB
    int*      csr    = (int*)(ebuf + (size_t)NB * CAPB);   // NB*CAPB
    int*      cnt    = csr + (size_t)NB * CAPB;            // N
    int*      rstart = cnt + N;                            // N
    float*    h2     = (float*)(rstart + N);               // N*16
    float*    als2   = h2 + (size_t)N * 16;                // N*2
    float*    ald2   = als2 + (size_t)N * 2;               // N*2

    hipMemsetAsync(bcur, 0, 512 * sizeof(int), stream);
    kb_scatter<<<(E + 4095) / 4096, 256, 0, stream>>>(src, dst, bcur, ebuf, E);
    kbA1<<<NB, 1024, 0, stream>>>(x, W1, as1, ad1, b1, W2, as2, ad2,
                                  bcur, ebuf, csr, cnt, rstart, h2, als2, ald2, N);
    kbA2<<<NB, 1024, 0, stream>>>(h2, als2, ald2, b2, lin_w, lin_b,
                                  csr, cnt, rstart, out, N);
}

// Round 15
// 169.755 us; speedup vs baseline: 1.0295x; 1.0295x over previous
//
#include <hip/hip_runtime.h>
#include <math.h>

// RiskGAT: 2-layer GAT (PyG GATConv, concat=True, self-loops) + linear + sigmoid.
// N=100000, E=1600000. L1: in=4,H=4,D=16 (F=64). L2: in=64,H=2,D=8 (F=16).
//
// R14 -> R15: REVERT to R11 (164.5us best; R12 lane-split +4us, R14 1024-thr +10us both
// regressed) with ONE change: kbA1 writes its sorted edge list IN-PLACE back to ebuf
// (coalesced int4; safe -- all reads of the region precede the writeback barrier) and
// cnt to global. kbA2 keeps R11's aggregation verbatim but deletes its duplicate
// hist+sort (2 edge passes + 3.2M LDS atomics): it rescans cnt (256 ints) for offsets
// and streams the sorted edges from ebuf (L2-resident, broadcast across 4 lanes).

#define NEG_SLOPE 0.2f
#define SHIFT 8                 // 256 nodes per bucket
#define BN 256
#define BMASK 255
#define CAPB 8192               // per-bucket region capacity (mean ~4092, >60-sigma)
#define STCAP 6144              // LDS stage capacity (mean ~4092, >30-sigma)

__device__ __forceinline__ float lrelu(float v) { return v >= 0.f ? v : NEG_SLOPE * v; }

// ---------------- Pass A: scatter packed (dlocal<<17 | src) into bucket regions ----------
__global__ void kb_scatter(const int* __restrict__ src, const int* __restrict__ dst,
                           int* __restrict__ bcur, unsigned* __restrict__ ebuf, int E) {
    __shared__ int lh[512], lbase[512], loff[512];
    int t = threadIdx.x;
    lh[t] = 0; lh[t + 256] = 0;
    __syncthreads();
    const int4* src4 = reinterpret_cast<const int4*>(src);
    const int4* dst4 = reinterpret_cast<const int4*>(dst);
    int base4 = blockIdx.x * 1024;           // 4096 edges = 1024 int4
    int myb[16];
    unsigned myv[16];
#pragma unroll
    for (int it = 0; it < 4; ++it) {
        int i4 = base4 + it * 256 + t;
        if (i4 * 4 < E) {                    // E % 4 == 0
            int4 s4 = src4[i4], d4 = dst4[i4];
            int ss[4] = {s4.x, s4.y, s4.z, s4.w};
            int dd[4] = {d4.x, d4.y, d4.z, d4.w};
#pragma unroll
            for (int c = 0; c < 4; ++c) {
                int b = dd[c] >> SHIFT;
                myb[it * 4 + c] = b;
                myv[it * 4 + c] = (unsigned)ss[c] | ((unsigned)(dd[c] & BMASK) << 17);
                atomicAdd(&lh[b], 1);
            }
        } else {
#pragma unroll
            for (int c = 0; c < 4; ++c) myb[it * 4 + c] = -1;
        }
    }
    __syncthreads();
    if (lh[t]) lbase[t] = atomicAdd(&bcur[t], lh[t]);
    if (lh[t + 256]) lbase[t + 256] = atomicAdd(&bcur[t + 256], lh[t + 256]);
    loff[t] = 0; loff[t + 256] = 0;
    __syncthreads();
#pragma unroll
    for (int it = 0; it < 16; ++it) {
        int b = myb[it];
        if (b >= 0) {
            int o = lbase[b] + atomicAdd(&loff[b], 1);
            if (o < CAPB) ebuf[(size_t)b * CAPB + o] = myv[it];
        }
    }
}

// ---------------- kbA1: per-bucket LDS sort + L1 agg + epilogue + L2 node phase -----------
// Also writes the sorted list back to ebuf (in place) + cnt, so kbA2 skips its sort.
__global__ void __launch_bounds__(512) kbA1(
        const float* __restrict__ x, const float* __restrict__ W1,
        const float* __restrict__ as1, const float* __restrict__ ad1,
        const float* __restrict__ b1, const float* __restrict__ W2,
        const float* __restrict__ as2, const float* __restrict__ ad2,
        const int* __restrict__ bcur, unsigned* __restrict__ ebuf,
        int* __restrict__ cnt,
        float* __restrict__ h2, float* __restrict__ als2, float* __restrict__ ald2, int N)
{
    __shared__ float sW[256], swals[16], swald[16], sb1[64], sW2[1024], sas2[16], sad2[16];
    __shared__ float aldL[BN * 5];       // [dl][head] stride 5
    __shared__ int nh[BN], ns[BN], stmp[BN];
    __shared__ int stage[STCAP];
    __shared__ float sE[128 * 65];       // 128 nodes/chunk x 64 e0, stride 65
    int t = threadIdx.x, b = blockIdx.x;
    if (t < 256) { sW[t] = W1[t]; nh[t] = 0; }
    for (int i = t; i < 1024; i += 512) sW2[i] = W2[i];
    if (t < 64) sb1[t] = b1[t];
    if (t >= 64 && t < 80) { sas2[t - 64] = as2[t - 64]; sad2[t - 64] = ad2[t - 64]; }
    __syncthreads();
    if (t < 16) {
        int head = t >> 2, i = t & 3;
        float s1 = 0.f, s2 = 0.f;
        for (int d = 0; d < 16; ++d) {
            float w = sW[i * 64 + head * 16 + d];
            s1 += w * as1[head * 16 + d];
            s2 += w * ad1[head * 16 + d];
        }
        swals[t] = s1;    // (W1_h @ a_src_h)[i]
        swald[t] = s2;
    }
    __syncthreads();

    int node0 = b << SHIFT;
    int nn = min(BN, N - node0);
    const float4* x4 = reinterpret_cast<const float4*>(x);
    int ne = min(bcur[b], STCAP);
    unsigned* eb = ebuf + (size_t)b * CAPB;

    // hist + per-dst ald precompute
    for (int i = t; i < ne; i += 512) atomicAdd(&nh[eb[i] >> 17], 1);
    for (int j = t; j < nn; j += 512) {
        float4 xd = x4[node0 + j];
#pragma unroll
        for (int h = 0; h < 4; ++h)
            aldL[j * 5 + h] = xd.x * swald[h * 4 + 0] + xd.y * swald[h * 4 + 1]
                            + xd.z * swald[h * 4 + 2] + xd.w * swald[h * 4 + 3];
    }
    __syncthreads();

    // scan (exclusive) -> ns cursor
    int vcnt = 0;
    if (t < 256) { vcnt = nh[t]; stmp[t] = vcnt; }
    __syncthreads();
#pragma unroll
    for (int off = 1; off < 256; off <<= 1) {
        int a = 0;
        if (t < 256 && t >= off) a = stmp[t - off];
        __syncthreads();
        if (t < 256) stmp[t] += a;
        __syncthreads();
    }
    if (t < 256) ns[t] = stmp[t] - vcnt;
    __syncthreads();

    // counting-sort into LDS stage (src only; dl implied by segment)
    for (int i = t; i < ne; i += 512) {
        unsigned pk = eb[i];
        int pos = atomicAdd(&ns[pk >> 17], 1);
        stage[pos] = (int)(pk & 0x1FFFFu);
    }
    __syncthreads();

    // ---- write sorted list back to ebuf (in place, coalesced) + cnt for kbA2 ----
    {
        int lim4 = ne & ~3;
        const int4* st4 = reinterpret_cast<const int4*>(stage);
        int4* e4 = reinterpret_cast<int4*>(eb);
        for (int i = t; i * 4 < lim4; i += 512) e4[i] = st4[i];
        for (int i = lim4 + t; i < ne; i += 512) eb[i] = (unsigned)stage[i];
        for (int j = t; j < nn; j += 512) cnt[node0 + j] = nh[j];
    }

    // ---- agg: 4 lanes/node (lane = head), 2 chunks x 128 nodes (R11 verbatim) ----
    int g = t >> 2, tt = t & 3;
    float wa0 = swals[tt * 4 + 0], wa1 = swals[tt * 4 + 1];
    float wa2 = swals[tt * 4 + 2], wa3 = swals[tt * 4 + 3];
#pragma unroll
    for (int c = 0; c < 2; ++c) {
        int j = c * 128 + g;
        int n = node0 + j;
        bool act = j < nn;
        int e = act ? nh[j] : 0;
        int st = act ? (ns[j] - e) : 0;     // cursor ended at start+cnt
        float aldv = act ? aldL[j * 5 + tt] : 0.f;
        float dA = 0.f, aA0 = 0.f, aA1 = 0.f, aA2 = 0.f, aA3 = 0.f;
        float dB = 0.f, aB0 = 0.f, aB1 = 0.f, aB2 = 0.f, aB3 = 0.f;
        int h = e >> 1;
        for (int i = 0; i < h; ++i) {
            int sA = stage[st + i];
            int sB = stage[st + h + i];
            float4 xA = x4[sA];
            float4 xB = x4[sB];
            float vA = lrelu(fmaf(xA.x, wa0, fmaf(xA.y, wa1, fmaf(xA.z, wa2, fmaf(xA.w, wa3, aldv)))));
            float vB = lrelu(fmaf(xB.x, wa0, fmaf(xB.y, wa1, fmaf(xB.z, wa2, fmaf(xB.w, wa3, aldv)))));
            float pA = __expf(vA);
            float pB = __expf(vB);
            dA += pA;                  dB += pB;
            aA0 = fmaf(pA, xA.x, aA0); aB0 = fmaf(pB, xB.x, aB0);
            aA1 = fmaf(pA, xA.y, aA1); aB1 = fmaf(pB, xB.y, aB1);
            aA2 = fmaf(pA, xA.z, aA2); aB2 = fmaf(pB, xB.z, aB2);
            aA3 = fmaf(pA, xA.w, aA3); aB3 = fmaf(pB, xB.w, aB3);
        }
        if (e & 1) {
            int s = stage[st + e - 1];
            float4 xs = x4[s];
            float v = lrelu(fmaf(xs.x, wa0, fmaf(xs.y, wa1, fmaf(xs.z, wa2, fmaf(xs.w, wa3, aldv)))));
            float p = __expf(v);
            dA += p;
            aA0 = fmaf(p, xs.x, aA0); aA1 = fmaf(p, xs.y, aA1);
            aA2 = fmaf(p, xs.z, aA2); aA3 = fmaf(p, xs.w, aA3);
        }
        // self loop + normalize
        float4 xn = act ? x4[n] : make_float4(0.f, 0.f, 0.f, 0.f);
        float als_s = xn.x * wa0 + xn.y * wa1 + xn.z * wa2 + xn.w * wa3;
        float ps = __expf(lrelu(als_s + aldv));
        float inv = 1.f / (dA + dB + ps + 1e-16f);
        float a0 = (aA0 + aB0 + ps * xn.x) * inv;
        float a1 = (aA1 + aB1 + ps * xn.y) * inv;
        float a2 = (aA2 + aB2 + ps * xn.z) * inv;
        float a3 = (aA3 + aB3 + ps * xn.w) * inv;

        // epilogue: e0 = elu((sum p*x)@W1_h + b1) -> sE row; own-column W2 dot
#pragma unroll
        for (int d = 0; d < 16; ++d) {
            int col = tt * 16 + d;
            float v = a0 * sW[col] + a1 * sW[64 + col] + a2 * sW[128 + col]
                    + a3 * sW[192 + col] + sb1[col];
            sE[g * 65 + col] = v > 0.f ? v : expm1f(v);
        }
        // 4 lanes of a group are in the same wave: row write->read is ordered
        float o0 = 0.f, o1 = 0.f, o2 = 0.f, o3 = 0.f;
#pragma unroll
        for (int k = 0; k < 64; ++k) {
            float ev = sE[g * 65 + k];
            o0 = fmaf(ev, sW2[k * 16 + tt * 4 + 0], o0);
            o1 = fmaf(ev, sW2[k * 16 + tt * 4 + 1], o1);
            o2 = fmaf(ev, sW2[k * 16 + tt * 4 + 2], o2);
            o3 = fmaf(ev, sW2[k * 16 + tt * 4 + 3], o3);
        }
        if (act)
            reinterpret_cast<float4*>(h2)[(size_t)n * 4 + tt] = make_float4(o0, o1, o2, o3);
        int head2 = tt >> 1, half = tt & 1;
        const float* s2p = sas2 + head2 * 8 + half * 4;
        const float* d2p = sad2 + head2 * 8 + half * 4;
        float qs = o0 * s2p[0] + o1 * s2p[1] + o2 * s2p[2] + o3 * s2p[3];
        float qd = o0 * d2p[0] + o1 * d2p[1] + o2 * d2p[2] + o3 * d2p[3];
        qs += __shfl_xor(qs, 1);
        qd += __shfl_xor(qd, 1);
        if (act && half == 0) {
            als2[n * 2 + head2] = qs;
            ald2[n * 2 + head2] = qd;
        }
    }
}

// ---------------- kbA2: L2 agg from pre-sorted ebuf (no sort) + linear head + sigmoid -----
__global__ void __launch_bounds__(512) kbA2(
        const float* __restrict__ h2, const float* __restrict__ als2,
        const float* __restrict__ ald2, const float* __restrict__ b2,
        const float* __restrict__ lw, const float* __restrict__ lb,
        const unsigned* __restrict__ ebuf, const int* __restrict__ cnt,
        float* __restrict__ out, int N)
{
    __shared__ int nh[BN], ns[BN], stmp[BN];
    __shared__ float ald2L[BN * 2];
    __shared__ float sb2[16], slw[16];
    int t = threadIdx.x, b = blockIdx.x;
    if (t < 16) { sb2[t] = b2[t]; slw[t] = lw[t]; }
    int node0 = b << SHIFT;
    int nn = min(BN, N - node0);
    if (t < 256) nh[t] = (t < nn) ? cnt[node0 + t] : 0;
    for (int j = t; j < nn * 2; j += 512) ald2L[j] = ald2[node0 * 2 + j];
    __syncthreads();
    // scan cnt -> exclusive start offsets (no edge pass)
    int vcnt = 0;
    if (t < 256) { vcnt = nh[t]; stmp[t] = vcnt; }
    __syncthreads();
#pragma unroll
    for (int off = 1; off < 256; off <<= 1) {
        int a = 0;
        if (t < 256 && t >= off) a = stmp[t - off];
        __syncthreads();
        if (t < 256) stmp[t] += a;
        __syncthreads();
    }
    if (t < 256) ns[t] = stmp[t] - vcnt;
    __syncthreads();

    const unsigned* eb = ebuf + (size_t)b * CAPB;
    const float4* h4 = reinterpret_cast<const float4*>(h2);
    const float2* als22 = reinterpret_cast<const float2*>(als2);
    int g = t >> 2, tt = t & 3, head = tt >> 1;
#pragma unroll
    for (int c = 0; c < 2; ++c) {
        int j = c * 128 + g;
        int n = node0 + j;
        bool act = j < nn;
        int e = act ? nh[j] : 0;
        int st = act ? ns[j] : 0;
        float aldv = act ? ald2L[j * 2 + head] : 0.f;
        float dA = 0.f, aA0 = 0.f, aA1 = 0.f, aA2 = 0.f, aA3 = 0.f;
        float dB = 0.f, aB0 = 0.f, aB1 = 0.f, aB2 = 0.f, aB3 = 0.f;
        int h = e >> 1;
        for (int i = 0; i < h; ++i) {
            int sA = (int)eb[st + i];
            int sB = (int)eb[st + h + i];
            float2 avA = als22[sA];
            float2 avB = als22[sB];
            float vA = lrelu((head ? avA.y : avA.x) + aldv);
            float vB = lrelu((head ? avB.y : avB.x) + aldv);
            float4 hA = h4[(size_t)sA * 4 + tt];
            float4 hB = h4[(size_t)sB * 4 + tt];
            float pA = __expf(vA);
            float pB = __expf(vB);
            dA += pA;                  dB += pB;
            aA0 = fmaf(pA, hA.x, aA0); aB0 = fmaf(pB, hB.x, aB0);
            aA1 = fmaf(pA, hA.y, aA1); aB1 = fmaf(pB, hB.y, aB1);
            aA2 = fmaf(pA, hA.z, aA2); aB2 = fmaf(pB, hB.z, aB2);
            aA3 = fmaf(pA, hA.w, aA3); aB3 = fmaf(pB, hB.w, aB3);
        }
        if (e & 1) {
            int s = (int)eb[st + e - 1];
            float2 av = als22[s];
            float v = lrelu((head ? av.y : av.x) + aldv);
            float4 hs = h4[(size_t)s * 4 + tt];
            float p = __expf(v);
            dA += p;
            aA0 = fmaf(p, hs.x, aA0); aA1 = fmaf(p, hs.y, aA1);
            aA2 = fmaf(p, hs.z, aA2); aA3 = fmaf(p, hs.w, aA3);
        }
        // self loop + normalize + head
        float dot = 0.f;
        if (act) {
            float2 av = als22[n];
            float ps = __expf(lrelu((head ? av.y : av.x) + aldv));
            float4 hn = h4[(size_t)n * 4 + tt];
            float inv = 1.f / (dA + dB + ps + 1e-16f);
            float v0 = (aA0 + aB0 + ps * hn.x) * inv + sb2[tt * 4 + 0];
            float v1 = (aA1 + aB1 + ps * hn.y) * inv + sb2[tt * 4 + 1];
            float v2 = (aA2 + aB2 + ps * hn.z) * inv + sb2[tt * 4 + 2];
            float v3 = (aA3 + aB3 + ps * hn.w) * inv + sb2[tt * 4 + 3];
            v0 = v0 > 0.f ? v0 : expm1f(v0);
            v1 = v1 > 0.f ? v1 : expm1f(v1);
            v2 = v2 > 0.f ? v2 : expm1f(v2);
            v3 = v3 > 0.f ? v3 : expm1f(v3);
            dot = v0 * slw[tt * 4 + 0] + v1 * slw[tt * 4 + 1]
                + v2 * slw[tt * 4 + 2] + v3 * slw[tt * 4 + 3];
        }
        dot += __shfl_xor(dot, 1);
        dot += __shfl_xor(dot, 2);
        if (act && tt == 0) out[n] = 1.f / (1.f + __expf(-(dot + lb[0])));
    }
}

extern "C" void kernel_launch(void* const* d_in, const int* in_sizes, int n_in,
                              void* d_out, int out_size, void* d_ws, size_t ws_size,
                              hipStream_t stream) {
    const float* x     = (const float*)d_in[0];
    const int*   eidx  = (const int*)d_in[1];
    const float* W1    = (const float*)d_in[2];
    const float* as1   = (const float*)d_in[3];
    const float* ad1   = (const float*)d_in[4];
    const float* b1    = (const float*)d_in[5];
    const float* W2    = (const float*)d_in[6];
    const float* as2   = (const float*)d_in[7];
    const float* ad2   = (const float*)d_in[8];
    const float* b2    = (const float*)d_in[9];
    const float* lin_w = (const float*)d_in[10];
    const float* lin_b = (const float*)d_in[11];
    float* out = (float*)d_out;

    const int N = in_sizes[0] / 4;
    const int E = in_sizes[1] / 2;
    const int* src = eidx;
    const int* dst = eidx + E;
    const int NB = (N + BMASK) >> SHIFT;   // 391 buckets of 256 nodes

    // ---- workspace layout ----
    int*      bcur = (int*)d_ws;                         // 512
    unsigned* ebuf = (unsigned*)(bcur + 512);            // NB*CAPB
    int*      cnt  = (int*)(ebuf + (size_t)NB * CAPB);   // N
    float*    h2   = (float*)(cnt + N);                  // N*16
    float*    als2 = h2 + (size_t)N * 16;                // N*2
    float*    ald2 = als2 + (size_t)N * 2;               // N*2

    hipMemsetAsync(bcur, 0, 512 * sizeof(int), stream);
    kb_scatter<<<(E + 4095) / 4096, 256, 0, stream>>>(src, dst, bcur, ebuf, E);
    kbA1<<<NB, 512, 0, stream>>>(x, W1, as1, ad1, b1, W2, as2, ad2,
                                 bcur, ebuf, cnt, h2, als2, ald2, N);
    kbA2<<<NB, 512, 0, stream>>>(h2, als2, ald2, b2, lin_w, lin_b,
                                 ebuf, cnt, out, N);
}

// Round 16
// 163.067 us; speedup vs baseline: 1.0718x; 1.0410x over previous
//
#include <hip/hip_runtime.h>
#include <math.h>

// RiskGAT: 2-layer GAT (PyG GATConv, concat=True, self-loops) + linear + sigmoid.
// N=100000, E=1600000. L1: in=4,H=4,D=16 (F=64). L2: in=64,H=2,D=8 (F=16).
//
// R16 = R11 VERBATIM (measured best: 164.5us). Post-R11 experiments all regressed:
//   R12 (csr handoff + lane-split):      168.5us
//   R14 (1024-thread occupancy push):    174.8us
//   R15 (in-place ebuf sort handoff):    169.8us
// Structure: memset + kb_scatter (bucket scatter, LDS-aggregated cursors) +
// kbA1 (per-bucket LDS counting sort -> 4-lane/node dual-stream L1 agg -> W1-linearity
// epilogue -> L2 node phase) + kbA2 (same sort -> L2 agg -> linear head -> sigmoid).
// Remaining time is latency-bound random gather + 2 mandatory edge passes; three
// independent structural escape attempts measured worse.

#define NEG_SLOPE 0.2f
#define SHIFT 8                 // 256 nodes per bucket
#define BN 256
#define BMASK 255
#define CAPB 8192               // per-bucket region capacity (mean ~4092, >60-sigma)
#define STCAP 6144              // LDS stage capacity (mean ~4092, >30-sigma)

__device__ __forceinline__ float lrelu(float v) { return v >= 0.f ? v : NEG_SLOPE * v; }

// ---------------- Pass A: scatter packed (dlocal<<17 | src) into bucket regions ----------
__global__ void kb_scatter(const int* __restrict__ src, const int* __restrict__ dst,
                           int* __restrict__ bcur, unsigned* __restrict__ ebuf, int E) {
    __shared__ int lh[512], lbase[512], loff[512];
    int t = threadIdx.x;
    lh[t] = 0; lh[t + 256] = 0;
    __syncthreads();
    const int4* src4 = reinterpret_cast<const int4*>(src);
    const int4* dst4 = reinterpret_cast<const int4*>(dst);
    int base4 = blockIdx.x * 1024;           // 4096 edges = 1024 int4
    int myb[16];
    unsigned myv[16];
#pragma unroll
    for (int it = 0; it < 4; ++it) {
        int i4 = base4 + it * 256 + t;
        if (i4 * 4 < E) {                    // E % 4 == 0
            int4 s4 = src4[i4], d4 = dst4[i4];
            int ss[4] = {s4.x, s4.y, s4.z, s4.w};
            int dd[4] = {d4.x, d4.y, d4.z, d4.w};
#pragma unroll
            for (int c = 0; c < 4; ++c) {
                int b = dd[c] >> SHIFT;
                myb[it * 4 + c] = b;
                myv[it * 4 + c] = (unsigned)ss[c] | ((unsigned)(dd[c] & BMASK) << 17);
                atomicAdd(&lh[b], 1);
            }
        } else {
#pragma unroll
            for (int c = 0; c < 4; ++c) myb[it * 4 + c] = -1;
        }
    }
    __syncthreads();
    if (lh[t]) lbase[t] = atomicAdd(&bcur[t], lh[t]);
    if (lh[t + 256]) lbase[t + 256] = atomicAdd(&bcur[t + 256], lh[t + 256]);
    loff[t] = 0; loff[t + 256] = 0;
    __syncthreads();
#pragma unroll
    for (int it = 0; it < 16; ++it) {
        int b = myb[it];
        if (b >= 0) {
            int o = lbase[b] + atomicAdd(&loff[b], 1);
            if (o < CAPB) ebuf[(size_t)b * CAPB + o] = myv[it];
        }
    }
}

// ---------------- kbA1: per-bucket LDS sort + L1 agg + epilogue + L2 node phase -----------
__global__ void __launch_bounds__(512) kbA1(
        const float* __restrict__ x, const float* __restrict__ W1,
        const float* __restrict__ as1, const float* __restrict__ ad1,
        const float* __restrict__ b1, const float* __restrict__ W2,
        const float* __restrict__ as2, const float* __restrict__ ad2,
        const int* __restrict__ bcur, const unsigned* __restrict__ ebuf,
        float* __restrict__ h2, float* __restrict__ als2, float* __restrict__ ald2, int N)
{
    __shared__ float sW[256], swals[16], swald[16], sb1[64], sW2[1024], sas2[16], sad2[16];
    __shared__ float aldL[BN * 5];       // [dl][head] stride 5
    __shared__ int nh[BN], ns[BN], stmp[BN];
    __shared__ int stage[STCAP];
    __shared__ float sE[128 * 65];       // 128 nodes/chunk x 64 e0, stride 65
    int t = threadIdx.x, b = blockIdx.x;
    if (t < 256) { sW[t] = W1[t]; nh[t] = 0; }
    for (int i = t; i < 1024; i += 512) sW2[i] = W2[i];
    if (t < 64) sb1[t] = b1[t];
    if (t >= 64 && t < 80) { sas2[t - 64] = as2[t - 64]; sad2[t - 64] = ad2[t - 64]; }
    __syncthreads();
    if (t < 16) {
        int head = t >> 2, i = t & 3;
        float s1 = 0.f, s2 = 0.f;
        for (int d = 0; d < 16; ++d) {
            float w = sW[i * 64 + head * 16 + d];
            s1 += w * as1[head * 16 + d];
            s2 += w * ad1[head * 16 + d];
        }
        swals[t] = s1;    // (W1_h @ a_src_h)[i]
        swald[t] = s2;
    }
    __syncthreads();

    int node0 = b << SHIFT;
    int nn = min(BN, N - node0);
    const float4* x4 = reinterpret_cast<const float4*>(x);
    int ne = min(bcur[b], STCAP);
    const unsigned* eb = ebuf + (size_t)b * CAPB;

    // hist + per-dst ald precompute
    for (int i = t; i < ne; i += 512) atomicAdd(&nh[eb[i] >> 17], 1);
    for (int j = t; j < nn; j += 512) {
        float4 xd = x4[node0 + j];
#pragma unroll
        for (int h = 0; h < 4; ++h)
            aldL[j * 5 + h] = xd.x * swald[h * 4 + 0] + xd.y * swald[h * 4 + 1]
                            + xd.z * swald[h * 4 + 2] + xd.w * swald[h * 4 + 3];
    }
    __syncthreads();

    // scan (exclusive) -> ns cursor
    int vcnt = 0;
    if (t < 256) { vcnt = nh[t]; stmp[t] = vcnt; }
    __syncthreads();
#pragma unroll
    for (int off = 1; off < 256; off <<= 1) {
        int a = 0;
        if (t < 256 && t >= off) a = stmp[t - off];
        __syncthreads();
        if (t < 256) stmp[t] += a;
        __syncthreads();
    }
    if (t < 256) ns[t] = stmp[t] - vcnt;
    __syncthreads();

    // counting-sort into LDS stage (src only; dl implied by segment)
    for (int i = t; i < ne; i += 512) {
        unsigned pk = eb[i];
        int pos = atomicAdd(&ns[pk >> 17], 1);
        stage[pos] = (int)(pk & 0x1FFFFu);
    }
    __syncthreads();

    // ---- agg: 4 lanes/node (lane = head), 2 chunks x 128 nodes ----
    int g = t >> 2, tt = t & 3;
    float wa0 = swals[tt * 4 + 0], wa1 = swals[tt * 4 + 1];
    float wa2 = swals[tt * 4 + 2], wa3 = swals[tt * 4 + 3];
#pragma unroll
    for (int c = 0; c < 2; ++c) {
        int j = c * 128 + g;
        int n = node0 + j;
        bool act = j < nn;
        int e = act ? nh[j] : 0;
        int st = act ? (ns[j] - e) : 0;     // cursor ended at start+cnt
        float aldv = act ? aldL[j * 5 + tt] : 0.f;
        float dA = 0.f, aA0 = 0.f, aA1 = 0.f, aA2 = 0.f, aA3 = 0.f;
        float dB = 0.f, aB0 = 0.f, aB1 = 0.f, aB2 = 0.f, aB3 = 0.f;
        int h = e >> 1;
        for (int i = 0; i < h; ++i) {
            int sA = stage[st + i];
            int sB = stage[st + h + i];
            float4 xA = x4[sA];
            float4 xB = x4[sB];
            float vA = lrelu(fmaf(xA.x, wa0, fmaf(xA.y, wa1, fmaf(xA.z, wa2, fmaf(xA.w, wa3, aldv)))));
            float vB = lrelu(fmaf(xB.x, wa0, fmaf(xB.y, wa1, fmaf(xB.z, wa2, fmaf(xB.w, wa3, aldv)))));
            float pA = __expf(vA);
            float pB = __expf(vB);
            dA += pA;                  dB += pB;
            aA0 = fmaf(pA, xA.x, aA0); aB0 = fmaf(pB, xB.x, aB0);
            aA1 = fmaf(pA, xA.y, aA1); aB1 = fmaf(pB, xB.y, aB1);
            aA2 = fmaf(pA, xA.z, aA2); aB2 = fmaf(pB, xB.z, aB2);
            aA3 = fmaf(pA, xA.w, aA3); aB3 = fmaf(pB, xB.w, aB3);
        }
        if (e & 1) {
            int s = stage[st + e - 1];
            float4 xs = x4[s];
            float v = lrelu(fmaf(xs.x, wa0, fmaf(xs.y, wa1, fmaf(xs.z, wa2, fmaf(xs.w, wa3, aldv)))));
            float p = __expf(v);
            dA += p;
            aA0 = fmaf(p, xs.x, aA0); aA1 = fmaf(p, xs.y, aA1);
            aA2 = fmaf(p, xs.z, aA2); aA3 = fmaf(p, xs.w, aA3);
        }
        // self loop + normalize
        float4 xn = act ? x4[n] : make_float4(0.f, 0.f, 0.f, 0.f);
        float als_s = xn.x * wa0 + xn.y * wa1 + xn.z * wa2 + xn.w * wa3;
        float ps = __expf(lrelu(als_s + aldv));
        float inv = 1.f / (dA + dB + ps + 1e-16f);
        float a0 = (aA0 + aB0 + ps * xn.x) * inv;
        float a1 = (aA1 + aB1 + ps * xn.y) * inv;
        float a2 = (aA2 + aB2 + ps * xn.z) * inv;
        float a3 = (aA3 + aB3 + ps * xn.w) * inv;

        // epilogue: e0 = elu((sum p*x)@W1_h + b1) -> sE row; own-column W2 dot
#pragma unroll
        for (int d = 0; d < 16; ++d) {
            int col = tt * 16 + d;
            float v = a0 * sW[col] + a1 * sW[64 + col] + a2 * sW[128 + col]
                    + a3 * sW[192 + col] + sb1[col];
            sE[g * 65 + col] = v > 0.f ? v : expm1f(v);
        }
        // 4 lanes of a group are in the same wave: row write->read is ordered
        float o0 = 0.f, o1 = 0.f, o2 = 0.f, o3 = 0.f;
#pragma unroll
        for (int k = 0; k < 64; ++k) {
            float ev = sE[g * 65 + k];
            o0 = fmaf(ev, sW2[k * 16 + tt * 4 + 0], o0);
            o1 = fmaf(ev, sW2[k * 16 + tt * 4 + 1], o1);
            o2 = fmaf(ev, sW2[k * 16 + tt * 4 + 2], o2);
            o3 = fmaf(ev, sW2[k * 16 + tt * 4 + 3], o3);
        }
        if (act)
            reinterpret_cast<float4*>(h2)[(size_t)n * 4 + tt] = make_float4(o0, o1, o2, o3);
        int head2 = tt >> 1, half = tt & 1;
        const float* s2p = sas2 + head2 * 8 + half * 4;
        const float* d2p = sad2 + head2 * 8 + half * 4;
        float qs = o0 * s2p[0] + o1 * s2p[1] + o2 * s2p[2] + o3 * s2p[3];
        float qd = o0 * d2p[0] + o1 * d2p[1] + o2 * d2p[2] + o3 * d2p[3];
        qs += __shfl_xor(qs, 1);
        qd += __shfl_xor(qd, 1);
        if (act && half == 0) {
            als2[n * 2 + head2] = qs;
            ald2[n * 2 + head2] = qd;
        }
    }
}

// ---------------- kbA2: per-bucket LDS sort + L2 agg + linear head + sigmoid --------------
__global__ void __launch_bounds__(512) kbA2(
        const float* __restrict__ h2, const float* __restrict__ als2,
        const float* __restrict__ ald2, const float* __restrict__ b2,
        const float* __restrict__ lw, const float* __restrict__ lb,
        const int* __restrict__ bcur, const unsigned* __restrict__ ebuf,
        float* __restrict__ out, int N)
{
    __shared__ int nh[BN], ns[BN], stmp[BN];
    __shared__ int stage[STCAP];
    __shared__ float ald2L[BN * 2];
    __shared__ float sb2[16], slw[16];
    int t = threadIdx.x, b = blockIdx.x;
    if (t < 256) nh[t] = 0;
    if (t < 16) { sb2[t] = b2[t]; slw[t] = lw[t]; }
    int node0 = b << SHIFT;
    int nn = min(BN, N - node0);
    __syncthreads();
    int ne = min(bcur[b], STCAP);
    const unsigned* eb = ebuf + (size_t)b * CAPB;
    for (int i = t; i < ne; i += 512) atomicAdd(&nh[eb[i] >> 17], 1);
    for (int j = t; j < nn * 2; j += 512) ald2L[j] = ald2[node0 * 2 + j];
    __syncthreads();
    int vcnt = 0;
    if (t < 256) { vcnt = nh[t]; stmp[t] = vcnt; }
    __syncthreads();
#pragma unroll
    for (int off = 1; off < 256; off <<= 1) {
        int a = 0;
        if (t < 256 && t >= off) a = stmp[t - off];
        __syncthreads();
        if (t < 256) stmp[t] += a;
        __syncthreads();
    }
    if (t < 256) ns[t] = stmp[t] - vcnt;
    __syncthreads();
    for (int i = t; i < ne; i += 512) {
        unsigned pk = eb[i];
        int pos = atomicAdd(&ns[pk >> 17], 1);
        stage[pos] = (int)(pk & 0x1FFFFu);
    }
    __syncthreads();

    // ---- agg: 4 lanes/node (lane tt owns h2 quad tt; head = tt>>1), 2 chunks ----
    int g = t >> 2, tt = t & 3, head = tt >> 1;
    const float4* h4 = reinterpret_cast<const float4*>(h2);
    const float2* als22 = reinterpret_cast<const float2*>(als2);
#pragma unroll
    for (int c = 0; c < 2; ++c) {
        int j = c * 128 + g;
        int n = node0 + j;
        bool act = j < nn;
        int e = act ? nh[j] : 0;
        int st = act ? (ns[j] - e) : 0;
        float aldv = act ? ald2L[j * 2 + head] : 0.f;
        float dA = 0.f, aA0 = 0.f, aA1 = 0.f, aA2 = 0.f, aA3 = 0.f;
        float dB = 0.f, aB0 = 0.f, aB1 = 0.f, aB2 = 0.f, aB3 = 0.f;
        int h = e >> 1;
        for (int i = 0; i < h; ++i) {
            int sA = stage[st + i];
            int sB = stage[st + h + i];
            float2 avA = als22[sA];
            float2 avB = als22[sB];
            float vA = lrelu((head ? avA.y : avA.x) + aldv);
            float vB = lrelu((head ? avB.y : avB.x) + aldv);
            float4 hA = h4[(size_t)sA * 4 + tt];
            float4 hB = h4[(size_t)sB * 4 + tt];
            float pA = __expf(vA);
            float pB = __expf(vB);
            dA += pA;                  dB += pB;
            aA0 = fmaf(pA, hA.x, aA0); aB0 = fmaf(pB, hB.x, aB0);
            aA1 = fmaf(pA, hA.y, aA1); aB1 = fmaf(pB, hB.y, aB1);
            aA2 = fmaf(pA, hA.z, aA2); aB2 = fmaf(pB, hB.z, aB2);
            aA3 = fmaf(pA, hA.w, aA3); aB3 = fmaf(pB, hB.w, aB3);
        }
        if (e & 1) {
            int s = stage[st + e - 1];
            float2 av = als22[s];
            float v = lrelu((head ? av.y : av.x) + aldv);
            float4 hs = h4[(size_t)s * 4 + tt];
            float p = __expf(v);
            dA += p;
            aA0 = fmaf(p, hs.x, aA0); aA1 = fmaf(p, hs.y, aA1);
            aA2 = fmaf(p, hs.z, aA2); aA3 = fmaf(p, hs.w, aA3);
        }
        // self loop + normalize + head
        float dot = 0.f;
        if (act) {
            float2 av = als22[n];
            float ps = __expf(lrelu((head ? av.y : av.x) + aldv));
            float4 hn = h4[(size_t)n * 4 + tt];
            float inv = 1.f / (dA + dB + ps + 1e-16f);
            float v0 = (aA0 + aB0 + ps * hn.x) * inv + sb2[tt * 4 + 0];
            float v1 = (aA1 + aB1 + ps * hn.y) * inv + sb2[tt * 4 + 1];
            float v2 = (aA2 + aB2 + ps * hn.z) * inv + sb2[tt * 4 + 2];
            float v3 = (aA3 + aB3 + ps * hn.w) * inv + sb2[tt * 4 + 3];
            v0 = v0 > 0.f ? v0 : expm1f(v0);
            v1 = v1 > 0.f ? v1 : expm1f(v1);
            v2 = v2 > 0.f ? v2 : expm1f(v2);
            v3 = v3 > 0.f ? v3 : expm1f(v3);
            dot = v0 * slw[tt * 4 + 0] + v1 * slw[tt * 4 + 1]
                + v2 * slw[tt * 4 + 2] + v3 * slw[tt * 4 + 3];
        }
        dot += __shfl_xor(dot, 1);
        dot += __shfl_xor(dot, 2);
        if (act && tt == 0) out[n] = 1.f / (1.f + __expf(-(dot + lb[0])));
    }
}

extern "C" void kernel_launch(void* const* d_in, const int* in_sizes, int n_in,
                              void* d_out, int out_size, void* d_ws, size_t ws_size,
                              hipStream_t stream) {
    const float* x     = (const float*)d_in[0];
    const int*   eidx  = (const int*)d_in[1];
    const float* W1    = (const float*)d_in[2];
    const float* as1   = (const float*)d_in[3];
    const float* ad1   = (const float*)d_in[4];
    const float* b1    = (const float*)d_in[5];
    const float* W2    = (const float*)d_in[6];
    const float* as2   = (const float*)d_in[7];
    const float* ad2   = (const float*)d_in[8];
    const float* b2    = (const float*)d_in[9];
    const float* lin_w = (const float*)d_in[10];
    const float* lin_b = (const float*)d_in[11];
    float* out = (float*)d_out;

    const int N = in_sizes[0] / 4;
    const int E = in_sizes[1] / 2;
    const int* src = eidx;
    const int* dst = eidx + E;
    const int NB = (N + BMASK) >> SHIFT;   // 391 buckets of 256 nodes

    // ---- workspace layout ----
    int*      bcur = (int*)d_ws;                         // 512
    unsigned* ebuf = (unsigned*)(bcur + 512);            // NB*CAPB
    float*    h2   = (float*)(ebuf + (size_t)NB * CAPB); // N*16
    float*    als2 = h2 + (size_t)N * 16;                // N*2
    float*    ald2 = als2 + (size_t)N * 2;               // N*2

    hipMemsetAsync(bcur, 0, 512 * sizeof(int), stream);
    kb_scatter<<<(E + 4095) / 4096, 256, 0, stream>>>(src, dst, bcur, ebuf, E);
    kbA1<<<NB, 512, 0, stream>>>(x, W1, as1, ad1, b1, W2, as2, ad2,
                                 bcur, ebuf, h2, als2, ald2, N);
    kbA2<<<NB, 512, 0, stream>>>(h2, als2, ald2, b2, lin_w, lin_b,
                                 bcur, ebuf, out, N);
}